// Round 11
// baseline (92.413 us; speedup 1.0000x reference)
//
#include <hip/hip_runtime.h>

// Problem constants (fixed by reference setup_inputs):
#define NB    8
#define NA    3
#define GSZ   128
#define NC    (NA*5)            // 15
#define NPRED (NA*GSZ*GSZ)      // 49152 preds per image
#define NTOT  (NB*NPRED)        // 393216
#define MGT   64                // gt rows
#define NWRD  (NPRED/32)        // 1536 mask words per image
#define NEGV  (-1e9f)
#define EPSV  (1e-16f)
#define NCHD  (NPRED/256)       // 192 decode chunks per image
#define DBLK  (NB*NCHD)         // 1536 decode blocks
#define GPASS 16                // gts per LDS gou-staging pass

#define LOG2E 1.442695040888963f
#define LN2   0.693147180559945f

// Fast transcendentals on the gfx950 special-function pipe (~1 ulp).
__device__ __forceinline__ float f_rcp(float x)  { return __builtin_amdgcn_rcpf(x); }
__device__ __forceinline__ float f_log(float x)  { return __builtin_amdgcn_logf(x) * LN2; }
__device__ __forceinline__ float f_tanh(float x) {
    float e = __builtin_amdgcn_exp2f(x * (2.0f * LOG2E));
    return 1.0f - 2.0f * f_rcp(e + 1.0f);
}
__device__ __forceinline__ float f_sigmoid(float x) {
    return f_rcp(1.0f + __builtin_amdgcn_exp2f(-x * LOG2E));
}

// GIoU/IoU exactly mirroring the reference arithmetic order (fp32).
__device__ __forceinline__ void gou_iou(const float4 p, const float4 g,
                                        float& iou, float& gou) {
    float px1 = p.x - p.z * 0.5f, px2 = p.x + p.z * 0.5f;
    float py1 = p.y - p.w * 0.5f, py2 = p.y + p.w * 0.5f;
    float gx1 = g.x - g.z * 0.5f, gx2 = g.x + g.z * 0.5f;
    float gy1 = g.y - g.w * 0.5f, gy2 = g.y + g.w * 0.5f;
    float iw = fmaxf(fminf(px2, gx2) - fmaxf(px1, gx1), 0.0f);
    float ih = fmaxf(fminf(py2, gy2) - fmaxf(py1, gy1), 0.0f);
    float inter = iw * ih;
    float ap = (px2 - px1) * (py2 - py1);
    float ag = (gx2 - gx1) * (gy2 - gy1);
    float un = ap + ag - inter;
    iou = inter / (un + EPSV);
    float cw = fmaxf(px2, gx2) - fminf(px1, gx1);
    float ch = fmaxf(py2, gy2) - fminf(py1, gy1);
    float ac = cw * ch;
    gou = iou - (ac - un) / (ac + EPSV);
}

// Decode pred p of image b straight from the raw tensor. Used identically in
// all kernels -> bit-identical P everywhere (no materialized pd array).
__device__ __forceinline__ float4 decode_P(const float* __restrict__ out,
                                           int b, int p) {
    int a = p / (GSZ * GSZ), r = p % (GSZ * GSZ);
    int y = r / GSZ, x = r % GSZ;
    const float* base = out + ((((size_t)b * NC + a * 5) * GSZ + y) * GSZ + x);
    const int st = GSZ * GSZ;
    float t0 = base[0], t1 = base[st], t2 = base[2 * st], t3 = base[3 * st];
    const float inv_gs = 1.0f / (float)GSZ;   // exact (pow2)
    float4 P;
    P.x = (f_tanh(t0) + 0.5f + (float)x) * inv_gs;
    P.y = (f_tanh(t1) + 0.5f + (float)y) * inv_gs;
    P.z = __builtin_amdgcn_exp2f(-(t2 * t2) * LOG2E);
    P.w = __builtin_amdgcn_exp2f(-(t3 * t3) * LOG2E);
    return P;
}

__device__ __forceinline__ float conf_c(const float* __restrict__ out,
                                        int b, int p) {
    int a = p / (GSZ * GSZ), r = p % (GSZ * GSZ);
    int y = r / GSZ, x = r % GSZ;
    const float* base = out + ((((size_t)b * NC + a * 5) * GSZ + y) * GSZ + x);
    float c = f_sigmoid(base[4 * GSZ * GSZ]);
    return fminf(fmaxf(c, 1e-7f), 1.0f - 1e-7f);
}

// K1: decode + thr bits + non-tp loss partials + per-gt argmax chunk
// partials. Each (pred,gt) gou is computed ONCE: the per-pred loop stages
// it in LDS (gmat, 16-gt passes) and the per-gt argmax re-reads it.
__global__ __launch_bounds__(256) void k_decode(const float* __restrict__ out,
                                                const float* __restrict__ gts,
                                                unsigned long long* __restrict__ thrbits,
                                                float* __restrict__ pval,
                                                int* __restrict__ ppd,
                                                double* __restrict__ partial,
                                                unsigned* __restrict__ done) {
    const int tid = threadIdx.x;
    const int b = blockIdx.x / NCHD;          // image
    const int ch = blockIdx.x % NCHD;         // chunk within image
    __shared__ float gmat[GPASS][256];        // staged gou values (16 KB)
    __shared__ float4 gbA[MGT];
    __shared__ int glist[MGT];
    __shared__ int ng_s;
    __shared__ double dsum[4][3];

    if (blockIdx.x == 0 && tid == 0) *done = 0u;   // ticket for fused final
    if (tid < MGT) {
        gbA[tid] = make_float4(gts[tid * 5 + 1], gts[tid * 5 + 2],
                               gts[tid * 5 + 3], gts[tid * 5 + 4]);
        bool v = (gts[tid * 5] == (float)b);
        unsigned long long m = __ballot(v);
        if (v) glist[(int)__popcll(m & ((1ull << tid) - 1ull))] = tid;  // ascending j
        if (tid == 0) ng_s = (int)__popcll(m);
    }

    const int p_loc = ch * 256 + tid;         // pred index within image
    float4 P = decode_P(out, b, p_loc);
    float c = conf_c(out, b, p_loc);
    __syncthreads();

    const int ng = ng_s;
    const int wave = tid >> 6, lane = tid & 63;
    float bg = NEGV, bi = 0.0f;               // per-pred fallback running max
    for (int base = 0; base < ng; base += GPASS) {
        int nn = min(ng - base, GPASS);
        // compute gou once per (pred, gt): ascending j, strict > = first max
        for (int m = 0; m < nn; m++) {
            float iu, go; gou_iou(P, gbA[glist[base + m]], iu, go);
            if (go > bg) { bg = go; bi = iu; }
            gmat[m][tid] = go;
        }
        __syncthreads();
        // per-gt argmax over this chunk from staged LDS; wave w takes gts
        // w, w+4,... Lane l owns preds 4l..4l+3 (ascending) -> strict >
        // keeps first max; cross-lane tiebreak idx-asc -> exact semantics.
        for (int m = wave; m < nn; m += 4) {
            float bv = NEGV; int bp = 0;
            #pragma unroll
            for (int k = 0; k < 4; k++) {
                int p = lane * 4 + k;
                float go = gmat[m][p];
                if (go > bv) { bv = go; bp = p; }
            }
            for (int off = 32; off > 0; off >>= 1) {
                float v2 = __shfl_down(bv, off, 64);
                int   p2 = __shfl_down(bp, off, 64);
                if (v2 > bv || (v2 == bv && p2 < bp)) { bv = v2; bp = p2; }
            }
            if (lane == 0) {
                int j = glist[base + m];
                pval[j * NCHD + ch] = bv;
                ppd[j * NCHD + ch]  = ch * 256 + bp;   // pred idx within image
            }
        }
        __syncthreads();                      // gmat reused next pass
    }

    // thr bit: fallback-argmax IoU > 0.5 (ng==0 -> pd_ious=0 -> thr=0)
    bool thr = (ng > 0) && (bi > 0.5f);
    {
        unsigned long long tm = __ballot(thr);
        const int idx = blockIdx.x * 256 + tid;
        if ((tid & 63) == 0) thrbits[idx >> 6] = tm;
    }

    // non-tp loss partials (as if tp=0 everywhere; fused finalizer corrects
    // the <=64 matched preds): ig = !thr here.
    {
        double a0 = 0.0, a1 = 0.0, a2 = 0.0;
        if (!thr) { a0 = 1.0; a1 = (double)(-f_log(1.0f - c)); a2 = (double)c * (double)c; }
        for (int off = 32; off > 0; off >>= 1) {
            a0 += __shfl_down(a0, off, 64);
            a1 += __shfl_down(a1, off, 64);
            a2 += __shfl_down(a2, off, 64);
        }
        if ((tid & 63) == 0) { dsum[wave][0] = a0; dsum[wave][1] = a1; dsum[wave][2] = a2; }
    }
    __syncthreads();
    if (tid < 3)
        partial[blockIdx.x * 3 + tid] =
            dsum[0][tid] + dsum[1][tid] + dsum[2][tid] + dsum[3][tid];
}

// K2: greedy matching (one workgroup per image) + FUSED finalize in the
// last-arriving block (8-block ticket). Matching: per-gt state in wave-0
// registers, ballot+shuffle rounds, block-wide rescans (recomputing P
// bit-identically from the raw tensor) only for stolen cached argmaxes.
// Replicates the reference while_loop exactly (first-occurrence argmax
// ties, winner scatter-max, first-j Amat selection).
#define MTH 1024
__global__ __launch_bounds__(MTH) void k_match(const float* __restrict__ gts,
                                               const float* __restrict__ pval,
                                               const int* __restrict__ ppd,
                                               const float* __restrict__ out,
                                               const double* __restrict__ partial,
                                               const unsigned long long* __restrict__ thrbits,
                                               int* __restrict__ mpred,
                                               unsigned* __restrict__ done,
                                               float* __restrict__ o) {
    const int b = blockIdx.x;
    const int tid = threadIdx.x;
    __shared__ unsigned mbits[NWRD];            // matched-pred bitmask
    __shared__ float4 gb[MGT];
    __shared__ float sh_v[MGT];
    __shared__ int   sh_p[MGT];
    __shared__ float sh_rv[16];
    __shared__ int   sh_rp[16];
    __shared__ unsigned long long sh_need;
    __shared__ int sh_cont;
    __shared__ double fw[16][9];

    for (int i = tid; i < NWRD; i += MTH) mbits[i] = 0u;
    if (tid < MGT)
        gb[tid] = make_float4(gts[tid * 5 + 1], gts[tid * 5 + 2],
                              gts[tid * 5 + 3], gts[tid * 5 + 4]);

    // parallel merge of decode's 192 chunk partials -> per-gt seed.
    // 16 threads per gt, 12 chunks each (ascending chunk = ascending pred:
    // strict > + idx-asc tiebreak == exact first-occurrence argmax).
    {
        int jt = tid >> 4, sub = tid & 15;
        float mv = NEGV; int mp = 0x7FFFFFFF;
        #pragma unroll
        for (int k = 0; k < NCHD / 16; k++) {
            int ch = sub * (NCHD / 16) + k;
            float v2 = pval[jt * NCHD + ch];
            int   p2 = ppd [jt * NCHD + ch];
            if (v2 > mv || (v2 == mv && p2 < mp)) { mv = v2; mp = p2; }
        }
        for (int off = 1; off < 16; off <<= 1) {          // xor-butterfly in 16-group
            float v2 = __shfl_xor(mv, off, 64);
            int   p2 = __shfl_xor(mp, off, 64);
            if (v2 > mv || (v2 == mv && p2 < mp)) { mv = v2; mp = p2; }
        }
        if (sub == 0) { sh_v[jt] = mv; sh_p[jt] = mp; }
    }
    __syncthreads();

    // wave-0 per-gt register state (invalid gts carry poisoned seeds from
    // unwritten pval/ppd rows -> mask them so no garbage LDS index forms)
    bool r_valid = false, r_sel = false;
    float r_cval = NEGV; int r_cpd = 0, r_mp = -1;
    if (tid < 64) {
        r_valid = (gts[tid * 5] == (float)b);
        r_cval = r_valid ? sh_v[tid] : NEGV;
        r_cpd  = r_valid ? sh_p[tid] : 0;
    }

    for (int round = 0; round < MGT + 2; ++round) {
        if (tid < 64) {
            bool active = r_valid && !r_sel;
            unsigned long long am = __ballot(active);
            bool stolen = active && ((mbits[r_cpd >> 5] >> (r_cpd & 31)) & 1u);
            unsigned long long nm = __ballot(stolen);
            if (tid == 0) { sh_cont = (am != 0ull) ? 1 : 0; sh_need = nm; }
        }
        __syncthreads();
        if (!sh_cont) break;
        unsigned long long need = sh_need;

        // rescans: only gts whose cached best pred got stolen (mask only
        // grows, so an un-stolen cached argmax is still exact).
        while (need) {
            int j = __ffsll((long long)need) - 1; need &= need - 1ull;
            float4 g = gb[j];
            float bv = NEGV; int bp = 0x7FFFFFFF;
            for (int p = tid; p < NPRED; p += MTH) {
                if ((mbits[p >> 5] >> (p & 31)) & 1u) continue;
                float iu, go; gou_iou(decode_P(out, b, p), g, iu, go);
                if (go > bv) { bv = go; bp = p; }        // strict > : first max
            }
            for (int off = 32; off > 0; off >>= 1) {
                float v2 = __shfl_down(bv, off, 64);
                int   p2 = __shfl_down(bp, off, 64);
                if (v2 > bv || (v2 == bv && p2 < bp)) { bv = v2; bp = p2; }
            }
            if ((tid & 63) == 0) { sh_rv[tid >> 6] = bv; sh_rp[tid >> 6] = bp; }
            __syncthreads();
            if (tid < 64) {
                float v = (tid < 16) ? sh_rv[tid] : NEGV;
                int   p = (tid < 16) ? sh_rp[tid] : 0x7FFFFFFF;
                for (int off = 1; off < 16; off <<= 1) {
                    float v2 = __shfl_xor(v, off, 64);
                    int   p2 = __shfl_xor(p, off, 64);
                    if (v2 > v || (v2 == v && p2 < p)) { v = v2; p = p2; }
                }
                v = __shfl(v, 0, 64); p = __shfl(p, 0, 64);
                if (tid == j) { r_cval = v; r_cpd = p; }
            }
            __syncthreads();
        }

        // conflict resolution, all in wave-0 registers + shuffles.
        if (tid < 64) {
            bool active = r_valid && !r_sel;
            float valj = active ? r_cval : NEGV;     // reference: inactive -> NEG
            int   pdj  = active ? r_cpd  : 0;        // reference: argmax of all-NEG = 0
            // winner[p] = scatter-max of valj over gts with pdj==p
            float w = NEGV;
            for (int j2 = 0; j2 < 64; j2++) {
                float v2 = __shfl(valj, j2, 64);
                int   p2 = __shfl(pdj,  j2, 64);
                if (p2 == pdj) w = fmaxf(w, v2);
            }
            // Amat first-j: first j2 with pdj2==p && valj2>=w
            unsigned long long fm = 0ull;
            for (int j2 = 0; j2 < 64; j2++) {
                float v2 = __shfl(valj, j2, 64);
                int   p2 = __shfl(pdj,  j2, 64);
                if (p2 == pdj && v2 >= w) fm |= (1ull << j2);
            }
            bool win = active && (w > NEGV * 0.5f) && fm &&
                       ((__ffsll((long long)fm) - 1) == tid);
            if (win) {
                r_sel = true;
                r_mp = pdj;
                atomicOr(&mbits[pdj >> 5], 1u << (pdj & 31));
            }
        }
        __syncthreads();   // mbits visible to all before next round / rescan
    }
    if (tid < 64) mpred[b * MGT + tid] = (r_valid && r_sel) ? r_mp : -1;
    __syncthreads();

    // ---- fused finalize: last-arriving block does the global reduction ----
    if (tid == 0) {
        __threadfence();                                  // release mpred
        unsigned old = atomicAdd(done, 1u);
        sh_cont = (old == NB - 1) ? 1 : 0;
    }
    __syncthreads();
    if (!sh_cont) return;
    __threadfence();                                      // acquire all writes

    // s: 0 cnt, 1 sxy, 2 swh, 3 sgou, 4 siou, 5 icnt, 6 sbce, 7 sinter, 8 sarea
    //   icnt  = A  + sum_tp (thr ? 1 : 0)
    //   sbce  = Bc + sum_tp [ -log(c) - (thr ? 0 : -log(1-c)) ]
    //   sarea = C2 + sum_tp (thr ? c^2 : 0)
    double s[9] = {0, 0, 0, 0, 0, 0, 0, 0, 0};
    for (int i = tid; i < DBLK; i += MTH) {
        s[5] += partial[i * 3 + 0];
        s[6] += partial[i * 3 + 1];
        s[8] += partial[i * 3 + 2];
    }
    if (tid < NB * MGT) {
        int bb = tid >> 6, j = tid & 63;
        int m = mpred[tid];
        if (m >= 0) {
            float4 g = gb[j];
            float4 P = decode_P(out, bb, m);
            float c = conf_c(out, bb, m);
            float pi, pg; gou_iou(P, g, pi, pg);
            int gidx = bb * NPRED + m;
            bool f = (thrbits[gidx >> 6] >> (gidx & 63)) & 1;  // decode's thr
            s[0] += 1.0;
            float dx = P.x - g.x, dy = P.y - g.y;
            s[1] += (double)(dx * dx) + (double)(dy * dy);
            float lw = f_log(P.z) - f_log(g.z);
            float lh = f_log(P.w) - f_log(g.w);
            s[2] += (double)(lw * lw) + (double)(lh * lh);
            s[3] += (double)pg;
            s[4] += (double)pi;
            s[5] += f ? 1.0 : 0.0;
            s[6] += (double)(-f_log(c)) - (f ? 0.0 : (double)(-f_log(1.0f - c)));
            s[7] += (double)c;
            s[8] += f ? (double)c * (double)c : 0.0;
        }
    }
    for (int k = 0; k < 9; k++) {
        double v = s[k];
        for (int off = 32; off > 0; off >>= 1) v += __shfl_down(v, off, 64);
        s[k] = v;
    }
    if ((tid & 63) == 0)
        for (int k = 0; k < 9; k++) fw[tid >> 6][k] = s[k];
    __syncthreads();
    if (tid == 0) {
        double acc[9];
        for (int k = 0; k < 9; k++) {
            double v = 0.0;
            for (int w = 0; w < 16; w++) v += fw[w][k];
            acc[k] = v;
        }
        double cnt_raw = acc[0];
        double cnt = cnt_raw > 1.0 ? cnt_raw : 1.0;
        double lxy  = acc[1] / cnt;
        double lwh  = acc[2] / cnt;
        double lgou = 1.0 - acc[3] / cnt;
        double liou = 1.0 - acc[4] / cnt;
        double icnt = acc[5] > 1.0 ? acc[5] : 1.0;
        double lbce = acc[6] / icnt;
        // gt_area = (tpf*ig).sum() == raw tp count (ig superset of tp), UNclamped
        double ldice = 1.0 - (2.0 * acc[7] + 1.0) / (acc[8] + cnt_raw + 1.0);
        double lconf = ldice + lbce;
        double tot = lconf + 2.0 * lgou + lwh + lxy;
        o[0] = (float)lxy;
        o[1] = (float)lwh;
        o[2] = (float)lconf;
        o[3] = (float)liou;
        o[4] = (float)lgou;
        o[5] = (float)tot;
    }
}

extern "C" void kernel_launch(void* const* d_in, const int* in_sizes, int n_in,
                              void* d_out, int out_size, void* d_ws, size_t ws_size,
                              hipStream_t stream) {
    const float* out_t = (const float*)d_in[0];  // [8,15,128,128]
    const float* gts   = (const float*)d_in[1];  // [64,5]
    char* ws = (char*)d_ws;
    size_t off = 0;
    unsigned* done    = (unsigned*)(ws + off);  off += 256;
    double*   partial = (double*)(ws + off);    off += (size_t)DBLK * 3 * 8;    // 36864
    float*    pval    = (float*)(ws + off);     off += (size_t)MGT * NCHD * 4;  // 49152
    int*      ppd     = (int*)(ws + off);       off += (size_t)MGT * NCHD * 4;  // 49152
    unsigned long long* thrbits = (unsigned long long*)(ws + off);
    off += (size_t)(NTOT / 64) * 8;                                             // 49152
    int*      mpred   = (int*)(ws + off);       off += (size_t)NB * MGT * 4;    // 2048
    float* o = (float*)d_out;

    k_decode<<<DBLK, 256, 0, stream>>>(out_t, gts, thrbits, pval, ppd, partial, done);
    k_match <<<NB, MTH, 0, stream>>>(gts, pval, ppd, out_t, partial, thrbits, mpred, done, o);
}